// Round 1
// 467.766 us; speedup vs baseline: 1.6468x; 1.6468x over previous
//
#include <hip/hip_runtime.h>
#include <hip/hip_bf16.h>
#include <math.h>

typedef __hip_bfloat16 bf16;
typedef unsigned short u16;
typedef __attribute__((ext_vector_type(8))) short bf16x8;
typedef __attribute__((ext_vector_type(4))) float f32x4;

__device__ __forceinline__ float us2f(u16 u) { return __uint_as_float(((unsigned)u) << 16); }
__device__ __forceinline__ u16 f2us(float f) { bf16 h = __float2bfloat16(f); return *(u16*)&h; }

__device__ __forceinline__ float wave_bcast_sum(float v) {
#pragma unroll
    for (int off = 32; off > 0; off >>= 1) v += __shfl_down(v, off);
    return __shfl(v, 0);
}

// ---------------------------------------------------------------------------
// f32 -> bf16 elementwise conversion (for weights)
// ---------------------------------------------------------------------------
__global__ __launch_bounds__(256) void k_f2b(const float* __restrict__ in, u16* __restrict__ out, int n) {
    int i = blockIdx.x * 256 + threadIdx.x;
    if (i < n) out[i] = f2us(in[i]);
}

// ---------------------------------------------------------------------------
// LN1 + roll(-3,-3,-3) + window partition. f32 in -> bf16 out (window order).
// ---------------------------------------------------------------------------
__global__ __launch_bounds__(256) void k_ln1_winpart(
    const float* __restrict__ x, const float* __restrict__ g, const float* __restrict__ b,
    u16* __restrict__ out)
{
    int lane = threadIdx.x & 63;
    int t = blockIdx.x * 4 + (threadIdx.x >> 6);
    int bidx = t / (64 * 343);
    int r = t - bidx * (64 * 343);
    int w = r / 343;
    int n = r - w * 343;
    int wd = w >> 4, wh = (w >> 2) & 3, ww = w & 3;
    int i = n / 49, rem = n - i * 49;
    int j = rem / 7, k = rem - j * 7;
    int sd = wd * 7 + i + 3; if (sd >= 28) sd -= 28;
    int sh = wh * 7 + j + 3; if (sh >= 28) sh -= 28;
    int sw = ww * 7 + k + 3; if (sw >= 28) sw -= 28;
    size_t src = ((((size_t)bidx * 28 + sd) * 28 + sh) * 28 + sw) * 192;
    float v0 = x[src + lane], v1 = x[src + lane + 64], v2 = x[src + lane + 128];
    float s  = wave_bcast_sum(v0 + v1 + v2);
    float mu = s * (1.0f / 192.0f);
    float s2 = wave_bcast_sum(v0 * v0 + v1 * v1 + v2 * v2);
    float rs = rsqrtf(s2 * (1.0f / 192.0f) - mu * mu + 1e-5f);
    u16* op = out + (size_t)t * 192;
    op[lane]       = f2us((v0 - mu) * rs * g[lane]       + b[lane]);
    op[lane + 64]  = f2us((v1 - mu) * rs * g[lane + 64]  + b[lane + 64]);
    op[lane + 128] = f2us((v2 - mu) * rs * g[lane + 128] + b[lane + 128]);
}

// ---------------------------------------------------------------------------
// LN2 over f32 residual x1 [M,192] (in d_out) -> bf16
// ---------------------------------------------------------------------------
__global__ __launch_bounds__(256) void k_ln2(
    const float* __restrict__ x1, const float* __restrict__ g, const float* __restrict__ b,
    u16* __restrict__ out)
{
    int lane = threadIdx.x & 63;
    int t = blockIdx.x * 4 + (threadIdx.x >> 6);
    const float* xp = x1 + (size_t)t * 192;
    float v0 = xp[lane], v1 = xp[lane + 64], v2 = xp[lane + 128];
    float s  = wave_bcast_sum(v0 + v1 + v2);
    float mu = s * (1.0f / 192.0f);
    float s2 = wave_bcast_sum(v0 * v0 + v1 * v1 + v2 * v2);
    float rs = rsqrtf(s2 * (1.0f / 192.0f) - mu * mu + 1e-5f);
    u16* op = out + (size_t)t * 192;
    op[lane]       = f2us((v0 - mu) * rs * g[lane]       + b[lane]);
    op[lane + 64]  = f2us((v1 - mu) * rs * g[lane + 64]  + b[lane + 64]);
    op[lane + 128] = f2us((v2 - mu) * rs * g[lane + 128] + b[lane + 128]);
}

// ---------------------------------------------------------------------------
// MFMA GEMM: out[m,n] = epi( sum_k A[m,k]*W[n,k] + bias[n] )
// A bf16 [M,K], W bf16 [Nc,K], bias f32. Tile BM=128, BN=64, BK=32.
// Frag layouts per m89/m91-verified mapping:
//   A-op: A[m=lane&15][k=(lane>>4)*8+j] ; C/D: row=(lane>>4)*4+r, col=lane&15.
// ---------------------------------------------------------------------------
template<int ACT, int OUT>
__global__ __launch_bounds__(256) void k_gemm_mfma(
    const u16* __restrict__ A, const u16* __restrict__ W, const float* __restrict__ bias,
    u16* __restrict__ outB, float* __restrict__ outF, const float* __restrict__ resid,
    int M, int Nc, int K)
{
    __shared__ __align__(16) u16 As[128 * 32];
    __shared__ __align__(16) u16 Bs[64 * 32];
    int tid = threadIdx.x;
    int lane = tid & 63, wv = tid >> 6;
    int quad = lane >> 4, l16 = lane & 15;
    int m0 = blockIdx.y << 7, n0 = blockIdx.x << 6;

    f32x4 acc[2][4] = {};
    int rowA0 = tid >> 2;                 // 0..63
    int rowA1 = rowA0 + 64;               // 64..127
    int koff = (tid & 3) << 3;            // 0,8,16,24

    for (int k0 = 0; k0 < K; k0 += 32) {
        uint4 a0 = *(const uint4*)(A + (size_t)(m0 + rowA0) * K + k0 + koff);
        uint4 a1 = *(const uint4*)(A + (size_t)(m0 + rowA1) * K + k0 + koff);
        uint4 b0 = *(const uint4*)(W + (size_t)(n0 + rowA0) * K + k0 + koff);
        __syncthreads();
        *(uint4*)&As[rowA0 * 32 + koff] = a0;
        *(uint4*)&As[rowA1 * 32 + koff] = a1;
        *(uint4*)&Bs[rowA0 * 32 + koff] = b0;
        __syncthreads();
        bf16x8 af[2], bfr[4];
#pragma unroll
        for (int mt = 0; mt < 2; mt++)
            af[mt] = *(const bf16x8*)&As[(wv * 32 + mt * 16 + l16) * 32 + quad * 8];
#pragma unroll
        for (int nt = 0; nt < 4; nt++)
            bfr[nt] = *(const bf16x8*)&Bs[(nt * 16 + l16) * 32 + quad * 8];
#pragma unroll
        for (int mt = 0; mt < 2; mt++)
#pragma unroll
            for (int nt = 0; nt < 4; nt++)
                acc[mt][nt] = __builtin_amdgcn_mfma_f32_16x16x32_bf16(af[mt], bfr[nt], acc[mt][nt], 0, 0, 0);
    }
#pragma unroll
    for (int mt = 0; mt < 2; mt++) {
#pragma unroll
        for (int nt = 0; nt < 4; nt++) {
#pragma unroll
            for (int r = 0; r < 4; r++) {
                int m = m0 + wv * 32 + mt * 16 + quad * 4 + r;
                int n = n0 + nt * 16 + l16;
                float v = acc[mt][nt][r] + bias[n];
                if (ACT == 1) v = 0.5f * v * (1.0f + erff(v * 0.70710678118654752f));
                size_t off = (size_t)m * Nc + n;
                if (OUT == 1) outB[off] = f2us(v);
                else outF[off] = resid[off] + v;
            }
        }
    }
}

// ---------------------------------------------------------------------------
// Fused windowed attention — MFMA version.
// One block = one (head, window, batch). 4 waves; wave owns row-tiles
// rt = wv, wv+4, ... (<22). N padded 343->352 (22 tiles of 16).
// QK^T: mfma_16x16x32 (hd=32 = one K-step). Softmax (no-max, proven safe
// here) on VALU; P round-tripped through per-wave LDS (C-layout -> A-layout
// transpose); PV: mfma over 11 key-chunks of 32, O normalized at end.
// LDS: Ks[352][40] (pad stride: 2-way banks), Vt[32][360] (V transposed so
// PV B-frag is ds_read_b128), Pb[4 waves][16][40], rpbs f32, codes.
// ---------------------------------------------------------------------------
__global__ __launch_bounds__(256) void k_attn(
    const u16* __restrict__ qkv, const float* __restrict__ rpb, u16* __restrict__ o_win)
{
    int head = blockIdx.x;
    int w = blockIdx.y;
    int bidx = blockIdx.z;
    __shared__ __align__(16) u16 Ks[352 * 40];
    __shared__ __align__(16) u16 Vt[32 * 360];
    __shared__ __align__(16) u16 Pb[4][16 * 40];
    __shared__ float rpbs[2197];
    __shared__ short tcode[343];
    __shared__ unsigned char lab[343];
    int tid = threadIdx.x;
    int lane = tid & 63, wv = tid >> 6;
    int quad = lane >> 4, l16 = lane & 15;
    size_t base = ((size_t)(bidx * 64 + w)) * 343;

    // Stage K (row-major, stride 40) and V (transposed) into LDS; zero-pad rows 343..351.
    for (int i = tid; i < 2816; i += 256) {           // 352 rows * 8 thread-groups
        int m = i >> 3;
        int d4 = (i & 7) << 2;
        ushort4 kv = {0, 0, 0, 0}, vv = {0, 0, 0, 0};
        if (m < 343) {
            size_t off = (base + m) * 576 + head * 32 + d4;
            kv = *(const ushort4*)(qkv + off + 192);
            vv = *(const ushort4*)(qkv + off + 384);
        }
        *(ushort4*)&Ks[m * 40 + d4] = kv;
        Vt[(d4 + 0) * 360 + m] = vv.x;
        Vt[(d4 + 1) * 360 + m] = vv.y;
        Vt[(d4 + 2) * 360 + m] = vv.z;
        Vt[(d4 + 3) * 360 + m] = vv.w;
    }
    for (int i = tid; i < 2197; i += 256)
        rpbs[i] = rpb[(size_t)i * 6 + head];
    int wd = w >> 4, wh = (w >> 2) & 3, ww = w & 3;
    for (int n = tid; n < 343; n += 256) {
        int i = n / 49, rem = n - i * 49;
        int j = rem / 7, k = rem - j * 7;
        tcode[n] = (short)(i * 169 + j * 13 + k);
        int gd = wd * 7 + i, gh = wh * 7 + j, gw = ww * 7 + k;
        int ld_ = (gd < 21) ? 0 : ((gd < 25) ? 1 : 2);
        int lh_ = (gh < 21) ? 0 : ((gh < 25) ? 1 : 2);
        int lw_ = (gw < 21) ? 0 : ((gw < 25) ? 1 : 2);
        lab[n] = (unsigned char)(ld_ * 9 + lh_ * 3 + lw_);
    }
    __syncthreads();

    const float scale = 0.17677669529663687f;  // 1/sqrt(32), applied post-MFMA
    u16* pbw = &Pb[wv][0];
    const f32x4 zero = {0.0f, 0.0f, 0.0f, 0.0f};

    for (int rt = wv; rt < 22; rt += 4) {
        // Q A-fragment straight from global: A[m=l16][k=quad*8+j]
        int na = rt * 16 + l16; if (na > 342) na = 342;
        bf16x8 af = *(const bf16x8*)(qkv + (base + na) * 576 + head * 32 + quad * 8);
        int tn[4], lr[4];
#pragma unroll
        for (int r = 0; r < 4; r++) {
            int n = rt * 16 + quad * 4 + r; if (n > 342) n = 342;
            tn[r] = (int)tcode[n] + 1098;
            lr[r] = lab[n];
        }
        f32x4 o0 = zero, o1 = zero;
        float psum[4] = {0.0f, 0.0f, 0.0f, 0.0f};
        for (int c = 0; c < 11; c++) {
            // --- QK^T: two 16x16 col-tiles of this 32-key chunk
            bf16x8 kb0 = *(const bf16x8*)&Ks[(c * 32 + l16) * 40 + quad * 8];
            bf16x8 kb1 = *(const bf16x8*)&Ks[(c * 32 + 16 + l16) * 40 + quad * 8];
            f32x4 s0 = __builtin_amdgcn_mfma_f32_16x16x32_bf16(af, kb0, zero, 0, 0, 0);
            f32x4 s1 = __builtin_amdgcn_mfma_f32_16x16x32_bf16(af, kb1, zero, 0, 0, 0);
            // --- bias + mask + exp; stash P (bf16) into per-wave LDS
            int m0i = c * 32 + l16;
            int m1i = m0i + 16;
            int mc0 = m0i > 342 ? 342 : m0i;
            int mc1 = m1i > 342 ? 342 : m1i;
            int tm0 = tcode[mc0], tm1 = tcode[mc1];
            int lm0 = lab[mc0],  lm1 = lab[mc1];
#pragma unroll
            for (int r = 0; r < 4; r++) {
                float s = s0[r] * scale + rpbs[tn[r] - tm0];
                if (lm0 != lr[r]) s -= 100.0f;
                float p = (m0i < 343) ? __expf(s) : 0.0f;
                u16 pu = f2us(p);
                psum[r] += us2f(pu);
                pbw[(quad * 4 + r) * 40 + l16] = pu;
                float s_ = s1[r] * scale + rpbs[tn[r] - tm1];
                if (lm1 != lr[r]) s_ -= 100.0f;
                float p_ = (m1i < 343) ? __expf(s_) : 0.0f;
                u16 pu_ = f2us(p_);
                psum[r] += us2f(pu_);
                pbw[(quad * 4 + r) * 40 + 16 + l16] = pu_;
            }
            // wave-synchronous: drain this wave's LDS writes before frag reads
            asm volatile("s_waitcnt lgkmcnt(0)" ::: "memory");
            // --- PV: P A-frag (transposed via LDS), V^T B-frags
            bf16x8 pa  = *(const bf16x8*)&pbw[l16 * 40 + quad * 8];
            bf16x8 vb0 = *(const bf16x8*)&Vt[l16 * 360 + c * 32 + quad * 8];
            bf16x8 vb1 = *(const bf16x8*)&Vt[(16 + l16) * 360 + c * 32 + quad * 8];
            o0 = __builtin_amdgcn_mfma_f32_16x16x32_bf16(pa, vb0, o0, 0, 0, 0);
            o1 = __builtin_amdgcn_mfma_f32_16x16x32_bf16(pa, vb1, o1, 0, 0, 0);
        }
        // row sums: reduce across the 16 l16 lanes (quad groups independent)
#pragma unroll
        for (int r = 0; r < 4; r++) {
#pragma unroll
            for (int off = 1; off < 16; off <<= 1)
                psum[r] += __shfl_xor(psum[r], off);
        }
#pragma unroll
        for (int r = 0; r < 4; r++) {
            int n = rt * 16 + quad * 4 + r;
            if (n < 343) {
                float inv = 1.0f / psum[r];
                u16* op = o_win + (base + n) * 192 + head * 32;
                op[l16]      = f2us(o0[r] * inv);
                op[l16 + 16] = f2us(o1[r] * inv);
            }
        }
    }
}

// ---------------------------------------------------------------------------
// Window reverse + roll(+3) + residual: x1 = x + rev(projw), f32 into d_out.
// ---------------------------------------------------------------------------
__global__ __launch_bounds__(256) void k_add_winrev(
    const float* __restrict__ x, const u16* __restrict__ projw, float* __restrict__ x1)
{
    int idx = blockIdx.x * 256 + threadIdx.x;
    int c = idx % 192;
    int tok = idx / 192;
    int sw_ = tok % 28, t1 = tok / 28;
    int sh_ = t1 % 28, t2 = t1 / 28;
    int sd_ = t2 % 28, bidx = t2 / 28;
    int rd = sd_ + 25; if (rd >= 28) rd -= 28;   // (d-3) mod 28
    int rh = sh_ + 25; if (rh >= 28) rh -= 28;
    int rw = sw_ + 25; if (rw >= 28) rw -= 28;
    int wd = rd / 7, i = rd - wd * 7;
    int wh = rh / 7, j = rh - wh * 7;
    int ww = rw / 7, k = rw - ww * 7;
    int w = (wd << 4) + (wh << 2) + ww;
    int n = (i * 7 + j) * 7 + k;
    size_t src = (((size_t)(bidx * 64 + w)) * 343 + n) * 192 + c;
    x1[idx] = x[idx] + us2f(projw[src]);
}

// ---------------------------------------------------------------------------
extern "C" void kernel_launch(void* const* d_in, const int* in_sizes, int n_in,
                              void* d_out, int out_size, void* d_ws, size_t ws_size,
                              hipStream_t stream)
{
    const float* x      = (const float*)d_in[0];
    const float* ln1_g  = (const float*)d_in[1];
    const float* ln1_b  = (const float*)d_in[2];
    const float* qkv_w  = (const float*)d_in[3];
    const float* qkv_b  = (const float*)d_in[4];
    const float* rpb    = (const float*)d_in[5];
    const float* proj_w = (const float*)d_in[6];
    const float* proj_b = (const float*)d_in[7];
    const float* ln2_g  = (const float*)d_in[8];
    const float* ln2_b  = (const float*)d_in[9];
    const float* fc1_w  = (const float*)d_in[10];
    const float* fc1_b  = (const float*)d_in[11];
    const float* fc2_w  = (const float*)d_in[12];
    const float* fc2_b  = (const float*)d_in[13];

    const int M = 43904;                   // tokens = B*nW*N (343 * 128-row tiles)
    const size_t MC  = (size_t)M * 192;
    const size_t MC2 = MC * 2;             // bytes of a bf16 [M,192] buffer

    char* ws = (char*)d_ws;
    u16* hA     = (u16*)ws;
    u16* qkvb   = (u16*)(ws + MC2);
    u16* projw  = (u16*)(ws + MC2);
    u16* gbuf   = (u16*)(ws + MC2);
    u16* fc1_wb = (u16*)(ws + MC2 + 17u * 1024 * 1024);
    u16* fc2_wb = (u16*)(ws + MC2 + 17u * 1024 * 1024 + 294912);
    float* out  = (float*)d_out;
    u16* qkv_wb  = (u16*)d_out;            // 110592 u16
    u16* proj_wb = (u16*)d_out + 110592;   //  36864 u16

    // Phase 1: LN1, QKV (MFMA), attention
    k_f2b<<<432, 256, 0, stream>>>(qkv_w, qkv_wb, 110592);
    k_f2b<<<144, 256, 0, stream>>>(proj_w, proj_wb, 36864);
    k_ln1_winpart<<<M / 4, 256, 0, stream>>>(x, ln1_g, ln1_b, hA);
    k_gemm_mfma<0, 1><<<dim3(9, 343), 256, 0, stream>>>(hA, qkv_wb, qkv_b, qkvb, nullptr, nullptr, M, 576, 192);
    k_attn<<<dim3(6, 64, 2), 256, 0, stream>>>(qkvb, rpb, hA);
    // fc weights into dead qkvb tail (must be after attn)
    k_f2b<<<576, 256, 0, stream>>>(fc1_w, fc1_wb, 147456);
    k_f2b<<<576, 256, 0, stream>>>(fc2_w, fc2_wb, 147456);
    // proj (MFMA), window-reverse + residual
    k_gemm_mfma<0, 1><<<dim3(3, 343), 256, 0, stream>>>(hA, proj_wb, proj_b, projw, nullptr, nullptr, M, 192, 192);
    k_add_winrev<<<(int)(MC / 256), 256, 0, stream>>>(x, projw, out);
    // Phase 2: LN2 + MLP (MFMA), 7 chunks of 6272 rows (49 x 128)
    k_ln2<<<M / 4, 256, 0, stream>>>(out, ln2_g, ln2_b, hA);
    const int CH = 6272;
    for (int c = 0; c < 7; c++) {
        size_t r0 = (size_t)c * CH;
        k_gemm_mfma<1, 1><<<dim3(12, 49), 256, 0, stream>>>(hA + r0 * 192, fc1_wb, fc1_b, gbuf, nullptr, nullptr, CH, 768, 192);
        k_gemm_mfma<0, 2><<<dim3(3, 49), 256, 0, stream>>>(gbuf, fc2_wb, fc2_b, nullptr, out + r0 * 192, out + r0 * 192, CH, 192, 768);
    }
}

// Round 2
// 340.899 us; speedup vs baseline: 2.2597x; 1.3722x over previous
//
#include <hip/hip_runtime.h>
#include <hip/hip_bf16.h>
#include <math.h>

typedef __hip_bfloat16 bf16;
typedef unsigned short u16;
typedef __attribute__((ext_vector_type(8))) short bf16x8;
typedef __attribute__((ext_vector_type(4))) short bf16x4;
typedef __attribute__((ext_vector_type(4))) float f32x4;

__device__ __forceinline__ float us2f(u16 u) { return __uint_as_float(((unsigned)u) << 16); }
__device__ __forceinline__ u16 f2us(float f) { bf16 h = __float2bfloat16(f); return *(u16*)&h; }

__device__ __forceinline__ float wave_bcast_sum(float v) {
#pragma unroll
    for (int off = 32; off > 0; off >>= 1) v += __shfl_down(v, off);
    return __shfl(v, 0);
}

// async global->LDS, 16B per lane. LDS dest must be wave-uniform base (+lane*16 by HW).
__device__ __forceinline__ void glds16(const u16* g, u16* l) {
    __builtin_amdgcn_global_load_lds((const __attribute__((address_space(1))) void*)g,
                                     (__attribute__((address_space(3))) void*)l, 16, 0, 0);
}

// ---------------------------------------------------------------------------
// f32 -> bf16 elementwise conversion (for weights)
// ---------------------------------------------------------------------------
__global__ __launch_bounds__(256) void k_f2b(const float* __restrict__ in, u16* __restrict__ out, int n) {
    int i = blockIdx.x * 256 + threadIdx.x;
    if (i < n) out[i] = f2us(in[i]);
}

// ---------------------------------------------------------------------------
// Precompute attention bias table biasT[h][n][m] = rpb[relidx(n,m)]*log2(e),
// m padded 343->352 (pad = 0; pad keys are killed via lab=255 in k_attn).
// ---------------------------------------------------------------------------
__global__ __launch_bounds__(256) void k_bias(const float* __restrict__ rpb, float* __restrict__ bt) {
    int idx = blockIdx.x * 256 + threadIdx.x;
    if (idx >= 6 * 343 * 352) return;
    int h = idx / (343 * 352);
    int r = idx - h * (343 * 352);
    int n = r / 352, m = r - n * 352;
    float v = 0.0f;
    if (m < 343) {
        int ni = n / 49, nr = n - ni * 49, nj = nr / 7, nk = nr - nj * 7;
        int mi = m / 49, mr = m - mi * 49, mj = mr / 7, mk = mr - mj * 7;
        int d = (ni - mi) * 169 + (nj - mj) * 13 + (nk - mk) + 1098;
        v = rpb[d * 6 + h] * 1.4426950408889634f;
    }
    bt[idx] = v;
}

// ---------------------------------------------------------------------------
// LN1 + roll(-3,-3,-3) + window partition. f32 in -> bf16 out (window order).
// ---------------------------------------------------------------------------
__global__ __launch_bounds__(256) void k_ln1_winpart(
    const float* __restrict__ x, const float* __restrict__ g, const float* __restrict__ b,
    u16* __restrict__ out)
{
    int lane = threadIdx.x & 63;
    int t = blockIdx.x * 4 + (threadIdx.x >> 6);
    int bidx = t / (64 * 343);
    int r = t - bidx * (64 * 343);
    int w = r / 343;
    int n = r - w * 343;
    int wd = w >> 4, wh = (w >> 2) & 3, ww = w & 3;
    int i = n / 49, rem = n - i * 49;
    int j = rem / 7, k = rem - j * 7;
    int sd = wd * 7 + i + 3; if (sd >= 28) sd -= 28;
    int sh = wh * 7 + j + 3; if (sh >= 28) sh -= 28;
    int sw = ww * 7 + k + 3; if (sw >= 28) sw -= 28;
    size_t src = ((((size_t)bidx * 28 + sd) * 28 + sh) * 28 + sw) * 192;
    float v0 = x[src + lane], v1 = x[src + lane + 64], v2 = x[src + lane + 128];
    float s  = wave_bcast_sum(v0 + v1 + v2);
    float mu = s * (1.0f / 192.0f);
    float s2 = wave_bcast_sum(v0 * v0 + v1 * v1 + v2 * v2);
    float rs = rsqrtf(s2 * (1.0f / 192.0f) - mu * mu + 1e-5f);
    u16* op = out + (size_t)t * 192;
    op[lane]       = f2us((v0 - mu) * rs * g[lane]       + b[lane]);
    op[lane + 64]  = f2us((v1 - mu) * rs * g[lane + 64]  + b[lane + 64]);
    op[lane + 128] = f2us((v2 - mu) * rs * g[lane + 128] + b[lane + 128]);
}

// ---------------------------------------------------------------------------
// Fused: window reverse + roll(+3) + residual add (f32 x1 out) + LN2 (bf16 out)
// One wave per spatial token.
// ---------------------------------------------------------------------------
__global__ __launch_bounds__(256) void k_add_winrev_ln2(
    const float* __restrict__ x, const u16* __restrict__ projw,
    const float* __restrict__ g, const float* __restrict__ b,
    float* __restrict__ x1, u16* __restrict__ h2)
{
    int lane = threadIdx.x & 63;
    int t = blockIdx.x * 4 + (threadIdx.x >> 6);
    int sw_ = t % 28, t1 = t / 28;
    int sh_ = t1 % 28, t2 = t1 / 28;
    int sd_ = t2 % 28, bidx = t2 / 28;
    int rd = sd_ + 25; if (rd >= 28) rd -= 28;   // (d-3) mod 28
    int rh = sh_ + 25; if (rh >= 28) rh -= 28;
    int rw = sw_ + 25; if (rw >= 28) rw -= 28;
    int wd = rd / 7, i = rd - wd * 7;
    int wh = rh / 7, j = rh - wh * 7;
    int ww = rw / 7, k = rw - ww * 7;
    int w = (wd << 4) + (wh << 2) + ww;
    int n = (i * 7 + j) * 7 + k;
    size_t src = (((size_t)(bidx * 64 + w)) * 343 + n) * 192;
    const float* xp = x + (size_t)t * 192;
    float v0 = xp[lane]       + us2f(projw[src + lane]);
    float v1 = xp[lane + 64]  + us2f(projw[src + lane + 64]);
    float v2 = xp[lane + 128] + us2f(projw[src + lane + 128]);
    float* op = x1 + (size_t)t * 192;
    op[lane] = v0; op[lane + 64] = v1; op[lane + 128] = v2;
    float s  = wave_bcast_sum(v0 + v1 + v2);
    float mu = s * (1.0f / 192.0f);
    float s2 = wave_bcast_sum(v0 * v0 + v1 * v1 + v2 * v2);
    float rs = rsqrtf(s2 * (1.0f / 192.0f) - mu * mu + 1e-5f);
    u16* hp = h2 + (size_t)t * 192;
    hp[lane]       = f2us((v0 - mu) * rs * g[lane]       + b[lane]);
    hp[lane + 64]  = f2us((v1 - mu) * rs * g[lane + 64]  + b[lane + 64]);
    hp[lane + 128] = f2us((v2 - mu) * rs * g[lane + 128] + b[lane + 128]);
}

// ---------------------------------------------------------------------------
// MFMA GEMM: out[m,n] = epi( sum_k A[m,k]*W[n,k] + bias[n] )
// A bf16 [M,K], W bf16 [Nc,K], bias f32. Tile BM=128, BN=64, BK=32.
// Staging via global_load_lds width-16 (LDS layout is linear in tid*16B).
// Frag layouts per m89/m91-verified mapping:
//   A-op: A[m=lane&15][k=(lane>>4)*8+j] ; C/D: row=(lane>>4)*4+r, col=lane&15.
// ---------------------------------------------------------------------------
template<int ACT, int OUT>
__global__ __launch_bounds__(256) void k_gemm_mfma(
    const u16* __restrict__ A, const u16* __restrict__ W, const float* __restrict__ bias,
    u16* __restrict__ outB, float* __restrict__ outF, const float* __restrict__ resid,
    int M, int Nc, int K)
{
    __shared__ __align__(16) u16 As[128 * 32];
    __shared__ __align__(16) u16 Bs[64 * 32];
    int tid = threadIdx.x;
    int lane = tid & 63, wv = tid >> 6;
    int quad = lane >> 4, l16 = lane & 15;
    int m0 = blockIdx.y << 7, n0 = blockIdx.x << 6;

    f32x4 acc[2][4] = {};
    int rowA0 = tid >> 2;                 // 0..63
    int rowA1 = rowA0 + 64;               // 64..127
    int koff = (tid & 3) << 3;            // 0,8,16,24

    const u16* gA0 = A + (size_t)(m0 + rowA0) * K + koff;
    const u16* gA1 = A + (size_t)(m0 + rowA1) * K + koff;
    const u16* gB0 = W + (size_t)(n0 + rowA0) * K + koff;
    u16* lA0 = &As[wv * 512];             // wave-uniform bases (lane*16B added by HW)
    u16* lA1 = &As[2048 + wv * 512];
    u16* lB0 = &Bs[wv * 512];

    for (int k0 = 0; k0 < K; k0 += 32) {
        glds16(gA0 + k0, lA0);
        glds16(gA1 + k0, lA1);
        glds16(gB0 + k0, lB0);
        __syncthreads();                  // drains vmcnt -> LDS data visible
        bf16x8 af[2], bfr[4];
#pragma unroll
        for (int mt = 0; mt < 2; mt++)
            af[mt] = *(const bf16x8*)&As[(wv * 32 + mt * 16 + l16) * 32 + quad * 8];
#pragma unroll
        for (int nt = 0; nt < 4; nt++)
            bfr[nt] = *(const bf16x8*)&Bs[(nt * 16 + l16) * 32 + quad * 8];
#pragma unroll
        for (int mt = 0; mt < 2; mt++)
#pragma unroll
            for (int nt = 0; nt < 4; nt++)
                acc[mt][nt] = __builtin_amdgcn_mfma_f32_16x16x32_bf16(af[mt], bfr[nt], acc[mt][nt], 0, 0, 0);
        __syncthreads();                  // all reads done before next overwrite
    }
#pragma unroll
    for (int mt = 0; mt < 2; mt++) {
#pragma unroll
        for (int nt = 0; nt < 4; nt++) {
#pragma unroll
            for (int r = 0; r < 4; r++) {
                int m = m0 + wv * 32 + mt * 16 + quad * 4 + r;
                int n = n0 + nt * 16 + l16;
                float v = acc[mt][nt][r] + bias[n];
                if (ACT == 1) v = 0.5f * v * (1.0f + erff(v * 0.70710678118654752f));
                size_t off = (size_t)m * Nc + n;
                if (OUT == 1) outB[off] = f2us(v);
                else outF[off] = resid[off] + v;
            }
        }
    }
}

// ---------------------------------------------------------------------------
// Fused windowed attention (MFMA). One block = (head, window, batch), 4 waves,
// wave owns row-tiles rt = wv, wv+4, ... (<22); N padded 343->352.
// Bias comes from precomputed global table biasT (f32, xlog2e); softmax uses
// exp2f; pad keys killed via lab=255. LDS ~52.8KB -> 3 blocks/CU.
// Ks stride 36 (b64-pair frag reads, 16 distinct bank starts), Vt[32][352],
// Pb stride 36 (per-wave P transpose C-layout -> A-layout).
// ---------------------------------------------------------------------------
__global__ __launch_bounds__(256) void k_attn(
    const u16* __restrict__ qkv, const float* __restrict__ biasT, u16* __restrict__ o_win)
{
    int head = blockIdx.x;
    int w = blockIdx.y;
    int bidx = blockIdx.z;
    __shared__ __align__(16) u16 Ks[352 * 36];
    __shared__ __align__(16) u16 Vt[32 * 352];
    __shared__ __align__(16) u16 Pb[4][16 * 36];
    __shared__ unsigned char lab[352];
    int tid = threadIdx.x;
    int lane = tid & 63, wv = tid >> 6;
    int quad = lane >> 4, l16 = lane & 15;
    size_t base = ((size_t)(bidx * 64 + w)) * 343;

    // Stage K (stride 36) and V transposed (Vt[d][m], m padded to 352, zero pad).
    for (int i = tid; i < 2816; i += 256) {
        int m = i >> 3;
        int d4 = (i & 7) << 2;
        ushort4 kv = {0, 0, 0, 0}, vv = {0, 0, 0, 0};
        if (m < 343) {
            size_t off = (base + m) * 576 + head * 32 + d4;
            kv = *(const ushort4*)(qkv + off + 192);
            vv = *(const ushort4*)(qkv + off + 384);
        }
        *(ushort4*)&Ks[m * 36 + d4] = kv;
        Vt[(d4 + 0) * 352 + m] = vv.x;
        Vt[(d4 + 1) * 352 + m] = vv.y;
        Vt[(d4 + 2) * 352 + m] = vv.z;
        Vt[(d4 + 3) * 352 + m] = vv.w;
    }
    int wd = w >> 4, wh = (w >> 2) & 3, ww = w & 3;
    for (int n = tid; n < 352; n += 256) {
        unsigned char lv = 255;                      // pad rows: label never matches
        if (n < 343) {
            int i = n / 49, rem = n - i * 49;
            int j = rem / 7, k = rem - j * 7;
            int gd = wd * 7 + i, gh = wh * 7 + j, gw = ww * 7 + k;
            int ld_ = (gd < 21) ? 0 : ((gd < 25) ? 1 : 2);
            int lh_ = (gh < 21) ? 0 : ((gh < 25) ? 1 : 2);
            int lw_ = (gw < 21) ? 0 : ((gw < 25) ? 1 : 2);
            lv = (unsigned char)(ld_ * 9 + lh_ * 3 + lw_);
        }
        lab[n] = lv;
    }
    __syncthreads();

    const float SL = 0.17677669529663687f * 1.4426950408889634f;  // scale * log2(e)
    u16* pbw = &Pb[wv][0];
    const f32x4 zero = {0.0f, 0.0f, 0.0f, 0.0f};

    for (int rt = wv; rt < 22; rt += 4) {
        int na = rt * 16 + l16; if (na > 342) na = 342;
        bf16x8 af = *(const bf16x8*)(qkv + (base + na) * 576 + head * 32 + quad * 8);
        int lr[4]; const float* bp[4];
#pragma unroll
        for (int r = 0; r < 4; r++) {
            int n = rt * 16 + quad * 4 + r; if (n > 342) n = 342;
            lr[r] = lab[n];
            bp[r] = biasT + ((size_t)(head * 343 + n)) * 352;
        }
        f32x4 o0 = zero, o1 = zero;
        float psum[4] = {0.0f, 0.0f, 0.0f, 0.0f};
        for (int c = 0; c < 11; c++) {
            int m0i = c * 32 + l16;
            int m1i = m0i + 16;
            // issue bias loads early (L2-resident, coalesced 64B/quad-row)
            float b0[4], b1[4];
#pragma unroll
            for (int r = 0; r < 4; r++) { b0[r] = bp[r][m0i]; b1[r] = bp[r][m1i]; }
            int lm0 = lab[m0i], lm1 = lab[m1i];
            // K frags: stride-36 rows, two b64 reads each (8B aligned)
            const u16* kr0 = &Ks[m0i * 36 + quad * 8];
            const u16* kr1 = &Ks[m1i * 36 + quad * 8];
            bf16x4 k0a = *(const bf16x4*)kr0, k0b = *(const bf16x4*)(kr0 + 4);
            bf16x4 k1a = *(const bf16x4*)kr1, k1b = *(const bf16x4*)(kr1 + 4);
            bf16x8 kb0 = __builtin_shufflevector(k0a, k0b, 0, 1, 2, 3, 4, 5, 6, 7);
            bf16x8 kb1 = __builtin_shufflevector(k1a, k1b, 0, 1, 2, 3, 4, 5, 6, 7);
            f32x4 s0 = __builtin_amdgcn_mfma_f32_16x16x32_bf16(af, kb0, zero, 0, 0, 0);
            f32x4 s1 = __builtin_amdgcn_mfma_f32_16x16x32_bf16(af, kb1, zero, 0, 0, 0);
#pragma unroll
            for (int r = 0; r < 4; r++) {
                float p0 = exp2f(fmaf(s0[r], SL, b0[r]));
                p0 = (lm0 == lr[r]) ? p0 : 0.0f;        // mask + pad kill
                psum[r] += p0;
                pbw[(quad * 4 + r) * 36 + l16] = f2us(p0);
                float p1 = exp2f(fmaf(s1[r], SL, b1[r]));
                p1 = (lm1 == lr[r]) ? p1 : 0.0f;
                psum[r] += p1;
                pbw[(quad * 4 + r) * 36 + 16 + l16] = f2us(p1);
            }
            asm volatile("s_waitcnt lgkmcnt(0)" ::: "memory");  // wave-sync Pb
            const u16* pr = &pbw[l16 * 36 + quad * 8];
            bf16x4 pa0 = *(const bf16x4*)pr, pa1 = *(const bf16x4*)(pr + 4);
            bf16x8 pa = __builtin_shufflevector(pa0, pa1, 0, 1, 2, 3, 4, 5, 6, 7);
            bf16x8 vb0 = *(const bf16x8*)&Vt[l16 * 352 + c * 32 + quad * 8];
            bf16x8 vb1 = *(const bf16x8*)&Vt[(16 + l16) * 352 + c * 32 + quad * 8];
            o0 = __builtin_amdgcn_mfma_f32_16x16x32_bf16(pa, vb0, o0, 0, 0, 0);
            o1 = __builtin_amdgcn_mfma_f32_16x16x32_bf16(pa, vb1, o1, 0, 0, 0);
        }
#pragma unroll
        for (int r = 0; r < 4; r++) {
#pragma unroll
            for (int off = 1; off < 16; off <<= 1)
                psum[r] += __shfl_xor(psum[r], off);
        }
#pragma unroll
        for (int r = 0; r < 4; r++) {
            int n = rt * 16 + quad * 4 + r;
            if (n < 343) {
                float inv = 1.0f / psum[r];
                u16* op = o_win + (base + n) * 192 + head * 32;
                op[l16]      = f2us(o0[r] * inv);
                op[l16 + 16] = f2us(o1[r] * inv);
            }
        }
    }
}

// ---------------------------------------------------------------------------
extern "C" void kernel_launch(void* const* d_in, const int* in_sizes, int n_in,
                              void* d_out, int out_size, void* d_ws, size_t ws_size,
                              hipStream_t stream)
{
    const float* x      = (const float*)d_in[0];
    const float* ln1_g  = (const float*)d_in[1];
    const float* ln1_b  = (const float*)d_in[2];
    const float* qkv_w  = (const float*)d_in[3];
    const float* qkv_b  = (const float*)d_in[4];
    const float* rpb    = (const float*)d_in[5];
    const float* proj_w = (const float*)d_in[6];
    const float* proj_b = (const float*)d_in[7];
    const float* ln2_g  = (const float*)d_in[8];
    const float* ln2_b  = (const float*)d_in[9];
    const float* fc1_w  = (const float*)d_in[10];
    const float* fc1_b  = (const float*)d_in[11];
    const float* fc2_w  = (const float*)d_in[12];
    const float* fc2_b  = (const float*)d_in[13];

    const int M = 43904;                   // tokens = B*nW*N (343 x 128-row tiles)
    const size_t MC  = (size_t)M * 192;
    const size_t MC2 = MC * 2;             // bytes of a bf16 [M,192] buffer

    // ws layout (peak unchanged at 67.4MB: qkvb end):
    //   hA    [0, 16.9MB)              bf16 [M,192]: hwin -> owin -> h2
    //   qkvb  [16.9, 67.4MB)           bf16 [M,576]; dead after attn, then:
    //     projw [16.9, 33.8MB)         bf16 [M,192]
    //     gbuf  [16.9, 50.7MB)         MLP hidden, 2 chunks of <=22016 rows
    //     fc1_wb/fc2_wb at [51MB, 51.6MB)
    // d_out scratch during phase 1: qkv_wb/proj_wb at [0,295KB), biasT f32 at [4MB,6.9MB)
    char* ws = (char*)d_ws;
    u16* hA     = (u16*)ws;
    u16* qkvb   = (u16*)(ws + MC2);
    u16* projw  = (u16*)(ws + MC2);
    u16* gbuf   = (u16*)(ws + MC2);
    u16* fc1_wb = (u16*)(ws + 51u * 1024 * 1024);
    u16* fc2_wb = (u16*)(ws + 51u * 1024 * 1024 + 294912);
    float* out  = (float*)d_out;
    u16* qkv_wb  = (u16*)d_out;            // 110592 u16
    u16* proj_wb = (u16*)d_out + 110592;   //  36864 u16
    float* biasT = (float*)((char*)d_out + 4u * 1024 * 1024);  // 724416 f32 = 2.9MB

    // Phase 1: weights->bf16, bias table, LN1, QKV (MFMA), attention
    k_f2b<<<432, 256, 0, stream>>>(qkv_w, qkv_wb, 110592);
    k_f2b<<<144, 256, 0, stream>>>(proj_w, proj_wb, 36864);
    k_bias<<<2830, 256, 0, stream>>>(rpb, biasT);
    k_ln1_winpart<<<M / 4, 256, 0, stream>>>(x, ln1_g, ln1_b, hA);
    k_gemm_mfma<0, 1><<<dim3(9, 343), 256, 0, stream>>>(hA, qkv_wb, qkv_b, qkvb, nullptr, nullptr, M, 576, 192);
    k_attn<<<dim3(6, 64, 2), 256, 0, stream>>>(qkvb, biasT, hA);
    // fc weights into dead qkvb tail (must be after attn)
    k_f2b<<<576, 256, 0, stream>>>(fc1_w, fc1_wb, 147456);
    k_f2b<<<576, 256, 0, stream>>>(fc2_w, fc2_wb, 147456);
    // proj (MFMA), fused window-reverse + residual + LN2
    k_gemm_mfma<0, 1><<<dim3(3, 343), 256, 0, stream>>>(hA, proj_wb, proj_b, projw, nullptr, nullptr, M, 192, 192);
    k_add_winrev_ln2<<<M / 4, 256, 0, stream>>>(x, projw, ln2_g, ln2_b, out, hA);
    // Phase 2: MLP (MFMA), 2 chunks (172 + 171 row-tiles)
    const int CH0 = 22016, CH1 = 21888;
    k_gemm_mfma<1, 1><<<dim3(12, 172), 256, 0, stream>>>(hA, fc1_wb, fc1_b, gbuf, nullptr, nullptr, CH0, 768, 192);
    k_gemm_mfma<0, 2><<<dim3(3, 172), 256, 0, stream>>>(gbuf, fc2_wb, fc2_b, nullptr, out, out, CH0, 192, 768);
    k_gemm_mfma<1, 1><<<dim3(12, 171), 256, 0, stream>>>(hA + (size_t)CH0 * 192, fc1_wb, fc1_b, gbuf, nullptr, nullptr, CH1, 768, 192);
    k_gemm_mfma<0, 2><<<dim3(3, 171), 256, 0, stream>>>(gbuf, fc2_wb, fc2_b, nullptr, out + (size_t)CH0 * 192, out + (size_t)CH0 * 192, CH1, 192, 768);
}